// Round 14
// baseline (6426.141 us; speedup 1.0000x reference)
//
#include <hip/hip_runtime.h>
#include <stdint.h>

#define BATCH 128
#define TSTEPS 250
#define NIN 700
#define NHID 1024
#define NBR 4
#define NOUT 20
#define KDIM 1724          // NIN + NHID
#define NR 4096            // NHID * NBR
#define VTH 0.5f

typedef float f32x4 __attribute__((ext_vector_type(4)));
typedef short s16x8 __attribute__((ext_vector_type(8)));

// ---------------- setup kernels ----------------

__global__ void setup_small(const float* __restrict__ tau_m1, const float* __restrict__ tau_n,
                            const float* __restrict__ tau_m2, const float* __restrict__ W2,
                            float* __restrict__ alpha1, float* __restrict__ beta,
                            float* __restrict__ alpha2, float* __restrict__ W2T) {
    int i = blockIdx.x * blockDim.x + threadIdx.x;
    if (i < NHID)  alpha1[i] = 1.f / (1.f + expf(-tau_m1[i]));
    if (i < NR)    beta[i]   = 1.f / (1.f + expf(-tau_n[i]));   // tau_n row-major [HID][BR] == flat r
    if (i < 32)    alpha2[i] = (i < NOUT) ? 1.f / (1.f + expf(-tau_m2[i])) : 0.f;
    if (i < NHID * 32) {                                        // W2T padded [1024][32]
        int j = i >> 5, o = i & 31;
        W2T[i] = (o < NOUT) ? W2[o * NHID + j] : 0.f;
    }
}

__device__ __forceinline__ uint16_t f2bf_rne(float x) {
    uint32_t u = __float_as_uint(x);
    return (uint16_t)((u + 0x7FFFu + ((u >> 16) & 1u)) >> 16);
}

// W1xT[k][r] (k<700) dense masked transpose (fp32 ffx GEMM), plus recurrent-weight
// MFMA B-frags (hi/lo), 32-r slices [R8-proven k/r bijection]:
//   frag[gb][nt2][ks][lane][j]: k = ks*32 + ((lane>>4)&3)*8 + j (ks=0..31),
//   r = gb*32 + nt2*16 + (lane&15)
__global__ void setup_weights(const float* __restrict__ W1, const int* __restrict__ mask,
                              float* __restrict__ W1xT, uint16_t* __restrict__ fragH,
                              uint16_t* __restrict__ fragL) {
    const int total1 = NIN * NR;            // 2,867,200
    const int total2 = 128 << 15;           // 4,194,304 frag elements
    for (int i = blockIdx.x * blockDim.x + threadIdx.x; i < total1 + total2;
         i += gridDim.x * blockDim.x) {
        if (i < total1) {
            int k = i >> 12, r = i & 4095;
            size_t src = (size_t)r * KDIM + k;
            W1xT[i] = W1[src] * (float)mask[src];
        } else {
            int e = i - total1;
            int j = e & 7, lane = (e >> 3) & 63, ks = (e >> 9) & 31;
            int nt2 = (e >> 14) & 1, gb = e >> 15;
            int k = ks * 32 + ((lane >> 4) & 3) * 8 + j;
            int r = gb * 32 + nt2 * 16 + (lane & 15);
            size_t src = (size_t)r * KDIM + NIN + k;
            float w = W1[src] * (float)mask[src];
            uint16_t hb = f2bf_rne(w);
            float hf = __uint_as_float((uint32_t)hb << 16);
            fragH[e] = hb;
            fragL[e] = f2bf_rne(w - hf);
        }
    }
}

__global__ void init_state(const float* __restrict__ mem1_0, const float* __restrict__ mem2_0,
                           float* __restrict__ mem1, float* __restrict__ mem2,
                           float* __restrict__ spk2, float* __restrict__ d_inp,
                           uint32_t* __restrict__ spk) {
    int i = blockIdx.x * blockDim.x + threadIdx.x;
    if (i < BATCH * NR) d_inp[i] = 0.f;
    if (i < BATCH * NHID) mem1[i] = mem1_0[i];
    if (i < BATCH * NOUT) { mem2[i] = mem2_0[i]; spk2[i] = 0.f; }
    // 4 slots x 2 groups x 2048 qwords = 32768 dwords. Zero = {tag 0, data 0}:
    // step-0 consumers expect tag 0 with zero spikes -> valid initial state, and
    // graph replays re-run this memset so absolute tags stay correct.
    if (i < 32768) spk[i] = 0u;
}

// ---------------- FFX GEMM (fp32, at vector roofline): ffx[dt][b][r] ----------------

#define GBM 128
#define GBN 128
#define GBK 16

__global__ __launch_bounds__(256) void ffx_gemm(const float* __restrict__ x,
                                                const float* __restrict__ W1xT,
                                                const float* __restrict__ b1,
                                                float* __restrict__ ffx, int t0) {
    __shared__ float As[GBK][GBM];
    __shared__ float Bs[GBK][GBN];
    int dt = blockIdx.x, bn = blockIdx.y;
    int tid = threadIdx.x;
    int tn = tid & 15, tm = tid >> 4;

    float acc[8][8];
#pragma unroll
    for (int i = 0; i < 8; ++i)
#pragma unroll
        for (int j = 0; j < 8; ++j) acc[i][j] = 0.f;

    int m_l = tid >> 1;
    const float* xrow = x + ((size_t)m_l * TSTEPS + t0 + dt) * NIN;
    int kh = (tid & 1) * 8;
    int kb = tid >> 4;
    int nb = (tid & 15) * 8;

    for (int k0 = 0; k0 < NIN; k0 += GBK) {
        float av[8];
#pragma unroll
        for (int u = 0; u < 8; ++u) {
            int k = k0 + kh + u;
            av[u] = (k < NIN) ? xrow[k] : 0.f;
        }
#pragma unroll
        for (int u = 0; u < 8; ++u) As[kh + u][m_l] = av[u];

        bool kok = (k0 + kb) < NIN;
        const float* bp = W1xT + (size_t)(k0 + kb) * NR + bn * GBN + nb;
        float bv[8];
#pragma unroll
        for (int u = 0; u < 8; ++u) bv[u] = kok ? bp[u] : 0.f;
#pragma unroll
        for (int u = 0; u < 8; ++u) Bs[kb][nb + u] = bv[u];

        __syncthreads();
#pragma unroll
        for (int kk = 0; kk < GBK; ++kk) {
            float a[8], b[8];
#pragma unroll
            for (int u = 0; u < 8; ++u) a[u] = As[kk][tm * 8 + u];
#pragma unroll
            for (int u = 0; u < 8; ++u) b[u] = Bs[kk][tn * 8 + u];
#pragma unroll
            for (int i = 0; i < 8; ++i)
#pragma unroll
                for (int j = 0; j < 8; ++j) acc[i][j] += a[i] * b[j];
        }
        __syncthreads();
    }

    float bias[8];
#pragma unroll
    for (int j = 0; j < 8; ++j) bias[j] = b1[bn * GBN + tn * 8 + j];
#pragma unroll
    for (int i = 0; i < 8; ++i) {
        int brow = tm * 8 + i;
        float* cp = ffx + ((size_t)dt * BATCH + brow) * NR + bn * GBN + tn * 8;
#pragma unroll
        for (int j = 0; j < 8; ++j) cp[j] = acc[i][j] + bias[j];
    }
}

// ---------------- persistent time-loop kernel: half-slot pipelined dataflow ----------------
// 256 blocks x 512 threads (8 waves); ~146 KB LDS -> 1 block/CU, all co-resident.
// Group G = blk>>7 owns batches G*64..+64; block gb = blk&127 owns r [gb*32, gb*32+32)
// = neurons [gb*8, gb*8+8). Groups never interact.
// SYNC = DATA (R13): spike word = 64-bit {data:32(hi), tag:32(lo)}, tag = absolute step
// the word feeds. NEW: halves of the slot are consumed PIPELINED —
//   issue loads for both halves -> retry LOW (producers 0..63, feeds ks 0..15) ->
//   S2a -> MFMA ks 0..15 (overlaps the high-half producer tail + load latency) ->
//   retry HIGH -> S2b -> MFMA ks 16..31 (same accumulators).
// The up-front wait is E[max over 64 producers], not 128; residual tail hides under
// ~1.3 us of MFMA. Staging is one contiguous 16B/thread load per half (fully coalesced).
// Raw word layout, publish, update, phase-2: identical to R13 (proven).

__global__ __launch_bounds__(512) void persist11(
    const float* __restrict__ alpha1, const float* __restrict__ beta,
    const float* __restrict__ alpha2, float* __restrict__ mem1,
    float* __restrict__ mem2, float* __restrict__ spk2,
    float* __restrict__ d_inp, const uint16_t* __restrict__ fragH_g,
    const uint16_t* __restrict__ fragL_g, const float* __restrict__ W2T,
    const float* __restrict__ ffx, const float* __restrict__ b2v,
    float* __restrict__ out, uint64_t* __restrict__ spk,
    int t0, int tc, int last) {
    __shared__ __align__(16) uint16_t lds_fh[32768];   // 64 KB  W1h slice hi (32 r)
    __shared__ __align__(16) uint16_t lds_fl[32768];   // 64 KB  W1h slice lo
    __shared__ uint32_t lds_raw[2048];                 // 8 KB   raw spike words
    __shared__ float lds_part[2560];                   // 10 KB  [4mt][32 r][20 b-pad]

    const int blk = blockIdx.x;
    const int tid = threadIdx.x;
    const int G   = blk >> 7;
    const int gb  = blk & 127;
    const int l   = tid & 63;
    const int wv  = tid >> 6;          // wave 0..7

    // ---- stage weight slice ONCE per chunk (128 KB)
    {
        const float4* sH = (const float4*)(fragH_g + (size_t)gb * 32768);
        const float4* sL = (const float4*)(fragL_g + (size_t)gb * 32768);
        for (int i4 = tid; i4 < 4096; i4 += 512) {
            ((float4*)lds_fh)[i4] = sH[i4];
            ((float4*)lds_fl)[i4] = sL[i4];
        }
    }

    // ---- mfma role: wave (mt, nt2)
    const int mt  = wv >> 1;
    const int nt2 = wv & 1;
    const int arow = mt * 16 + (l & 15);       // local batch row
    const int lhi  = (l >> 4) & 3;
    const int rawoff = arow >> 2;              // dword-in-block for this batch row
    const int ashf   = (arow & 3) * 8;         // byte shift for this batch row

    // ---- update role: tid = b_local*8 + nrn
    const int ub = tid >> 3;                   // local batch 0..63
    const int un = tid & 7;                    // neuron-in-block 0..7
    const int bg_ = G * 64 + ub;               // global batch
    const int n_g = gb * 8 + un;               // global neuron
    const int r0  = gb * 32 + un * 4;          // global r base (4 branches)
    const f32x4 bet = *(const f32x4*)&beta[r0];
    const float al  = alpha1[n_g];
    f32x4 di = *(const f32x4*)&d_inp[(size_t)bg_ * NR + r0];
    float mm = mem1[bg_ * NHID + n_g];

    // ---- layer-2 role: blocks gb<16 of each group, 4 batches each
    const int o2 = tid & 31;
    const int sub = tid >> 5;                  // 0..15
    const bool l2blk = (gb < 16) && ((sub & 3) == 0);
    const int b2l = gb * 4 + (sub >> 2);
    const int b2g = G * 64 + b2l;
    float m2 = 0.f, s2v = 0.f, a2 = 0.f, bo = 0.f;
    if (l2blk && o2 < NOUT) {
        a2 = alpha2[o2];
        bo = b2v[o2];
        m2 = mem2[b2g * NOUT + o2];
        s2v = spk2[b2g * NOUT + o2];
    }

    const int iters = tc + (last ? 1 : 0);
    for (int it = 0; it < iters; ++it) {
        const int tt = t0 + it;

        // ---- prefetch ffx (independent of spikes; overlaps the poll)
        f32x4 ff = {0.f, 0.f, 0.f, 0.f};
        if (tt < TSTEPS)
            ff = *(const f32x4*)(ffx + (size_t)it * (BATCH * NR) + (size_t)bg_ * NR + r0);

        __syncthreads();   // S1: all lds_raw/lds_part readers of prev iter done

        const uint64_t* sp = spk + ((size_t)(tt & 3) * 2 + G) * 2048;
        const uint32_t tag = (uint32_t)tt;

        // ---- issue BOTH halves' loads (contiguous 16B/thread each half)
        uint64_t vlo0 = __hip_atomic_load(&sp[2 * tid],        __ATOMIC_RELAXED, __HIP_MEMORY_SCOPE_AGENT);
        uint64_t vlo1 = __hip_atomic_load(&sp[2 * tid + 1],    __ATOMIC_RELAXED, __HIP_MEMORY_SCOPE_AGENT);
        uint64_t vhi0 = __hip_atomic_load(&sp[1024 + 2 * tid], __ATOMIC_RELAXED, __HIP_MEMORY_SCOPE_AGENT);
        uint64_t vhi1 = __hip_atomic_load(&sp[1025 + 2 * tid], __ATOMIC_RELAXED, __HIP_MEMORY_SCOPE_AGENT);

        // ---- retry LOW half (producers 0..63) and stage it
        while ((uint32_t)vlo0 != tag) {
            __builtin_amdgcn_s_sleep(1);
            vlo0 = __hip_atomic_load(&sp[2 * tid], __ATOMIC_RELAXED, __HIP_MEMORY_SCOPE_AGENT);
        }
        while ((uint32_t)vlo1 != tag) {
            __builtin_amdgcn_s_sleep(1);
            vlo1 = __hip_atomic_load(&sp[2 * tid + 1], __ATOMIC_RELAXED, __HIP_MEMORY_SCOPE_AGENT);
        }
        lds_raw[2 * tid]     = (uint32_t)(vlo0 >> 32);
        lds_raw[2 * tid + 1] = (uint32_t)(vlo1 >> 32);
        __syncthreads();   // S2a: low half ready

        f32x4 accH = {0.f, 0.f, 0.f, 0.f};
        f32x4 accL = {0.f, 0.f, 0.f, 0.f};
        const int fbase = nt2 * 32;

        // ---------- MFMA ks 0..15 (low half; overlaps high-half tail) ----------
        if (tt < TSTEPS) {
#pragma unroll 4
            for (int ks = 0; ks < 16; ++ks) {
                uint32_t bits = (lds_raw[((ks << 2) + lhi) * 16 + rawoff] >> ashf) & 0xFFu;
                union { uint32_t u[4]; s16x8 v; } a;
                a.u[0] = ((bits & 1u)  ? 0x3F80u : 0u) | ((bits & 2u)   ? 0x3F800000u : 0u);
                a.u[1] = ((bits & 4u)  ? 0x3F80u : 0u) | ((bits & 8u)   ? 0x3F800000u : 0u);
                a.u[2] = ((bits & 16u) ? 0x3F80u : 0u) | ((bits & 32u)  ? 0x3F800000u : 0u);
                a.u[3] = ((bits & 64u) ? 0x3F80u : 0u) | ((bits & 128u) ? 0x3F800000u : 0u);
                const s16x8 bh = *(const s16x8*)&lds_fh[((fbase + ks) * 64 + l) * 8];
                const s16x8 bl = *(const s16x8*)&lds_fl[((fbase + ks) * 64 + l) * 8];
                accH = __builtin_amdgcn_mfma_f32_16x16x32_bf16(a.v, bh, accH, 0, 0, 0);
                accL = __builtin_amdgcn_mfma_f32_16x16x32_bf16(a.v, bl, accL, 0, 0, 0);
            }
        }

        // ---- retry HIGH half (producers 64..127) — tail has had ~1.3us to finish
        while ((uint32_t)vhi0 != tag) {
            __builtin_amdgcn_s_sleep(1);
            vhi0 = __hip_atomic_load(&sp[1024 + 2 * tid], __ATOMIC_RELAXED, __HIP_MEMORY_SCOPE_AGENT);
        }
        while ((uint32_t)vhi1 != tag) {
            __builtin_amdgcn_s_sleep(1);
            vhi1 = __hip_atomic_load(&sp[1025 + 2 * tid], __ATOMIC_RELAXED, __HIP_MEMORY_SCOPE_AGENT);
        }
        lds_raw[1024 + 2 * tid] = (uint32_t)(vhi0 >> 32);
        lds_raw[1025 + 2 * tid] = (uint32_t)(vhi1 >> 32);
        __syncthreads();   // S2b: high half ready

        // ---------- MFMA ks 16..31 (same accumulators) + parts store ----------
        if (tt < TSTEPS) {
#pragma unroll 4
            for (int ks = 16; ks < 32; ++ks) {
                uint32_t bits = (lds_raw[((ks << 2) + lhi) * 16 + rawoff] >> ashf) & 0xFFu;
                union { uint32_t u[4]; s16x8 v; } a;
                a.u[0] = ((bits & 1u)  ? 0x3F80u : 0u) | ((bits & 2u)   ? 0x3F800000u : 0u);
                a.u[1] = ((bits & 4u)  ? 0x3F80u : 0u) | ((bits & 8u)   ? 0x3F800000u : 0u);
                a.u[2] = ((bits & 16u) ? 0x3F80u : 0u) | ((bits & 32u)  ? 0x3F800000u : 0u);
                a.u[3] = ((bits & 64u) ? 0x3F80u : 0u) | ((bits & 128u) ? 0x3F800000u : 0u);
                const s16x8 bh = *(const s16x8*)&lds_fh[((fbase + ks) * 64 + l) * 8];
                const s16x8 bl = *(const s16x8*)&lds_fl[((fbase + ks) * 64 + l) * 8];
                accH = __builtin_amdgcn_mfma_f32_16x16x32_bf16(a.v, bh, accH, 0, 0, 0);
                accL = __builtin_amdgcn_mfma_f32_16x16x32_bf16(a.v, bl, accL, 0, 0, 0);
            }
            f32x4 d;
#pragma unroll
            for (int q = 0; q < 4; ++q) d[q] = accH[q] + accL[q];
            // parts [mt][32 r_local][20 b-pad]; C/D col=l&15 (r), row=(l>>4)*4+q (b) [m89]
            float* pp = lds_part + ((mt * 32 + nt2 * 16 + (l & 15)) * 20 + ((l >> 4) & 3) * 4);
            *(float4*)pp = *(float4*)&d;
        }
        __syncthreads();   // S3: parts ready

        // ---------- phase 1b: dendrite + mem1 + spike (tagged 64-bit publishes) ----------
        if (tt < TSTEPS) {
            const int rl0 = un * 4;
            float s[4];
#pragma unroll
            for (int q = 0; q < 4; ++q)
                s[q] = lds_part[((ub >> 4) * 32 + rl0 + q) * 20 + (ub & 15)];
#pragma unroll
            for (int q = 0; q < 4; ++q)
                di[q] = bet[q] * di[q] + (1.f - bet[q]) * (s[q] + ff[q]);
            float lsum = (di[0] + di[1]) + (di[2] + di[3]);
            float sp_prev = (float)((lds_raw[gb * 16 + (ub >> 2)] >> ((ub & 3) * 8 + un)) & 1u);
            float mn = mm * al + (1.f - al) * lsum - VTH * sp_prev;
            mm = mn;
            bool spkb = (mn - VTH) > 0.f;
            unsigned long long bal = __ballot(spkb);  // bit l = (batch wv*8 + l>>3, nrn l&7)
            uint64_t* spn = spk + ((size_t)((tt + 1) & 3) * 2 + G) * 2048;
            const uint64_t ntag = (uint64_t)(uint32_t)(tt + 1);
            if (l == 0)
                __hip_atomic_store(&spn[gb * 16 + wv * 2],
                                   ((uint64_t)(uint32_t)bal << 32) | ntag,
                                   __ATOMIC_RELAXED, __HIP_MEMORY_SCOPE_AGENT);
            if (l == 32)
                __hip_atomic_store(&spn[gb * 16 + wv * 2 + 1],
                                   ((uint64_t)(uint32_t)(bal >> 32) << 32) | ntag,
                                   __ATOMIC_RELAXED, __HIP_MEMORY_SCOPE_AGENT);
        }

        // ---------- phase 2 (step tt-1): layer 2 + log_softmax ----------
        // These 16 blocks/group skew late, then find next step's tags already set.
        if (tt > 0 && l2blk) {
            const int sh2 = (b2l & 3) * 8;
            const int off2 = b2l >> 2;
            float d2 = bo;
            for (int g2 = 0; g2 < 128; ++g2) {
                uint32_t bits = (lds_raw[g2 * 16 + off2] >> sh2) & 0xFFu;
                while (bits) {
                    int p = __builtin_ctz(bits);
                    bits &= bits - 1;
                    d2 += W2T[(((g2 << 3) + p) << 5) + o2];
                }
            }
            float m2n = m2 * a2 + (1.f - a2) * d2 - VTH * s2v;
            m2 = m2n;
            s2v = ((m2n - VTH) > 0.f) ? 1.f : 0.f;
            float v = (o2 < NOUT) ? m2n : -3.4e38f;
#pragma unroll
            for (int off = 16; off >= 1; off >>= 1) v = fmaxf(v, __shfl_xor(v, off, 32));
            float e = (o2 < NOUT) ? expf(m2n - v) : 0.f;
            float ssum = e;
#pragma unroll
            for (int off = 16; off >= 1; off >>= 1) ssum += __shfl_xor(ssum, off, 32);
            if (o2 < NOUT) out[((size_t)b2g * NOUT + o2) * TSTEPS + (tt - 1)] = (m2n - v) - logf(ssum);
        }
    }

    // ---- save state for next chunk
    *(f32x4*)&d_inp[(size_t)bg_ * NR + r0] = di;
    mem1[bg_ * NHID + n_g] = mm;
    if (l2blk && o2 < NOUT) {
        mem2[b2g * NOUT + o2] = m2;
        spk2[b2g * NOUT + o2] = s2v;
    }
}

// ---------------- host ----------------

extern "C" void kernel_launch(void* const* d_in, const int* in_sizes, int n_in,
                              void* d_out, int out_size, void* d_ws, size_t ws_size,
                              hipStream_t stream) {
    const float* x      = (const float*)d_in[0];
    const float* W1     = (const float*)d_in[1];
    const float* b1     = (const float*)d_in[2];
    const float* tau_m1 = (const float*)d_in[3];
    const float* tau_n  = (const float*)d_in[4];
    const float* W2     = (const float*)d_in[5];
    const float* b2     = (const float*)d_in[6];
    const float* tau_m2 = (const float*)d_in[7];
    const float* mem1_0 = (const float*)d_in[8];
    const float* mem2_0 = (const float*)d_in[9];
    const int*   mask   = (const int*)d_in[10];
    float* out = (float*)d_out;

    float* ws = (float*)d_ws;
    size_t F = 0;
    float* alpha1 = ws + F; F += 1024;
    float* beta   = ws + F; F += 4096;
    float* alpha2 = ws + F; F += 32;
    float* mem1   = ws + F; F += BATCH * NHID;
    float* mem2   = ws + F; F += BATCH * NOUT;
    float* spk2   = ws + F; F += BATCH * NOUT;
    float* d_inp  = ws + F; F += BATCH * NR;
    float* W1xT   = ws + F; F += (size_t)NIN * NR;
    uint16_t* fragH = (uint16_t*)(ws + F); F += (size_t)(128 << 15) / 2;   // W1h frags hi
    uint16_t* fragL = (uint16_t*)(ws + F); F += (size_t)(128 << 15) / 2;   // W1h frags lo
    float* W2T    = ws + F; F += NHID * 32;
    F = (F + 1) & ~(size_t)1;                                  // 8B align for qwords
    uint64_t* spk = (uint64_t*)(ws + F); F += 32768;           // 4 slots x 2 grp x 2048 qw
    float* ffx = ws + F;

    size_t ws_f = ws_size / 4;
    size_t avail = (ws_f > F) ? (ws_f - F) : 0;
    size_t per_t = (size_t)BATCH * NR;          // 524288 floats per timestep
    int Tc = (int)(avail / per_t);
    if (Tc < 1) Tc = 1;
    if (Tc > TSTEPS) Tc = TSTEPS;

    hipLaunchKernelGGL(setup_small, dim3(128), dim3(256), 0, stream,
                       tau_m1, tau_n, tau_m2, W2, alpha1, beta, alpha2, W2T);
    hipLaunchKernelGGL(setup_weights, dim3(2048), dim3(256), 0, stream,
                       W1, mask, W1xT, fragH, fragL);
    hipLaunchKernelGGL(init_state, dim3(2048), dim3(256), 0, stream,
                       mem1_0, mem2_0, mem1, mem2, spk2, d_inp, (uint32_t*)spk);

    int chunk_start = 0;
    while (chunk_start < TSTEPS) {
        int tc = TSTEPS - chunk_start;
        if (tc > Tc) tc = Tc;
        int last = (chunk_start + tc >= TSTEPS) ? 1 : 0;

        hipLaunchKernelGGL(ffx_gemm, dim3(tc, 32), dim3(256), 0, stream,
                           x, W1xT, b1, ffx, chunk_start);
        hipLaunchKernelGGL(persist11, dim3(256), dim3(512), 0, stream,
                           alpha1, beta, alpha2, mem1, mem2, spk2, d_inp, fragH, fragL,
                           W2T, ffx, b2, out, spk, chunk_start, tc, last);

        chunk_start += tc;
    }
}

// Round 15
// 6107.787 us; speedup vs baseline: 1.0521x; 1.0521x over previous
//
#include <hip/hip_runtime.h>
#include <stdint.h>

#define BATCH 128
#define TSTEPS 250
#define NIN 700
#define NHID 1024
#define NBR 4
#define NOUT 20
#define KDIM 1724          // NIN + NHID
#define NR 4096            // NHID * NBR
#define VTH 0.5f

typedef float f32x4 __attribute__((ext_vector_type(4)));
typedef short s16x8 __attribute__((ext_vector_type(8)));

// ---------------- setup kernels ----------------

__global__ void setup_small(const float* __restrict__ tau_m1, const float* __restrict__ tau_n,
                            const float* __restrict__ tau_m2, const float* __restrict__ W2,
                            float* __restrict__ alpha1, float* __restrict__ beta,
                            float* __restrict__ alpha2, float* __restrict__ W2T) {
    int i = blockIdx.x * blockDim.x + threadIdx.x;
    if (i < NHID)  alpha1[i] = 1.f / (1.f + expf(-tau_m1[i]));
    if (i < NR)    beta[i]   = 1.f / (1.f + expf(-tau_n[i]));   // tau_n row-major [HID][BR] == flat r
    if (i < 32)    alpha2[i] = (i < NOUT) ? 1.f / (1.f + expf(-tau_m2[i])) : 0.f;
    if (i < NHID * 32) {                                        // W2T padded [1024][32]
        int j = i >> 5, o = i & 31;
        W2T[i] = (o < NOUT) ? W2[o * NHID + j] : 0.f;
    }
}

__device__ __forceinline__ uint16_t f2bf_rne(float x) {
    uint32_t u = __float_as_uint(x);
    return (uint16_t)((u + 0x7FFFu + ((u >> 16) & 1u)) >> 16);
}

// W1xT[k][r] (k<700) dense masked transpose (fp32 ffx GEMM), plus recurrent-weight
// MFMA B-frags (hi/lo), 32-r slices [R8-proven k/r bijection]:
//   frag[gb][nt2][ks][lane][j]: k = ks*32 + ((lane>>4)&3)*8 + j (ks=0..31),
//   r = gb*32 + nt2*16 + (lane&15)
__global__ void setup_weights(const float* __restrict__ W1, const int* __restrict__ mask,
                              float* __restrict__ W1xT, uint16_t* __restrict__ fragH,
                              uint16_t* __restrict__ fragL) {
    const int total1 = NIN * NR;            // 2,867,200
    const int total2 = 128 << 15;           // 4,194,304 frag elements
    for (int i = blockIdx.x * blockDim.x + threadIdx.x; i < total1 + total2;
         i += gridDim.x * blockDim.x) {
        if (i < total1) {
            int k = i >> 12, r = i & 4095;
            size_t src = (size_t)r * KDIM + k;
            W1xT[i] = W1[src] * (float)mask[src];
        } else {
            int e = i - total1;
            int j = e & 7, lane = (e >> 3) & 63, ks = (e >> 9) & 31;
            int nt2 = (e >> 14) & 1, gb = e >> 15;
            int k = ks * 32 + ((lane >> 4) & 3) * 8 + j;
            int r = gb * 32 + nt2 * 16 + (lane & 15);
            size_t src = (size_t)r * KDIM + NIN + k;
            float w = W1[src] * (float)mask[src];
            uint16_t hb = f2bf_rne(w);
            float hf = __uint_as_float((uint32_t)hb << 16);
            fragH[e] = hb;
            fragL[e] = f2bf_rne(w - hf);
        }
    }
}

__global__ void init_state(const float* __restrict__ mem1_0, const float* __restrict__ mem2_0,
                           float* __restrict__ mem1, float* __restrict__ mem2,
                           float* __restrict__ spk2, float* __restrict__ d_inp,
                           uint32_t* __restrict__ spkg, uint32_t* __restrict__ bar) {
    int i = blockIdx.x * blockDim.x + threadIdx.x;
    if (i < BATCH * NR) d_inp[i] = 0.f;
    if (i < BATCH * NHID) mem1[i] = mem1_0[i];
    if (i < BATCH * NOUT) { mem2[i] = mem2_0[i]; spk2[i] = 0.f; }
    if (i < 8192) spkg[i] = 0u;   // 2 slots x 2 groups x 2048 raw spike words
    if (i < 2048) bar[i] = 0u;    // 2 independent barrier regions — re-zeroed every launch
}

// ---------------- FFX GEMM (fp32, at vector roofline): ffx[dt][b][r] ----------------

#define GBM 128
#define GBN 128
#define GBK 16

__global__ __launch_bounds__(256) void ffx_gemm(const float* __restrict__ x,
                                                const float* __restrict__ W1xT,
                                                const float* __restrict__ b1,
                                                float* __restrict__ ffx, int t0) {
    __shared__ float As[GBK][GBM];
    __shared__ float Bs[GBK][GBN];
    int dt = blockIdx.x, bn = blockIdx.y;
    int tid = threadIdx.x;
    int tn = tid & 15, tm = tid >> 4;

    float acc[8][8];
#pragma unroll
    for (int i = 0; i < 8; ++i)
#pragma unroll
        for (int j = 0; j < 8; ++j) acc[i][j] = 0.f;

    int m_l = tid >> 1;
    const float* xrow = x + ((size_t)m_l * TSTEPS + t0 + dt) * NIN;
    int kh = (tid & 1) * 8;
    int kb = tid >> 4;
    int nb = (tid & 15) * 8;

    for (int k0 = 0; k0 < NIN; k0 += GBK) {
        float av[8];
#pragma unroll
        for (int u = 0; u < 8; ++u) {
            int k = k0 + kh + u;
            av[u] = (k < NIN) ? xrow[k] : 0.f;
        }
#pragma unroll
        for (int u = 0; u < 8; ++u) As[kh + u][m_l] = av[u];

        bool kok = (k0 + kb) < NIN;
        const float* bp = W1xT + (size_t)(k0 + kb) * NR + bn * GBN + nb;
        float bv[8];
#pragma unroll
        for (int u = 0; u < 8; ++u) bv[u] = kok ? bp[u] : 0.f;
#pragma unroll
        for (int u = 0; u < 8; ++u) Bs[kb][nb + u] = bv[u];

        __syncthreads();
#pragma unroll
        for (int kk = 0; kk < GBK; ++kk) {
            float a[8], b[8];
#pragma unroll
            for (int u = 0; u < 8; ++u) a[u] = As[kk][tm * 8 + u];
#pragma unroll
            for (int u = 0; u < 8; ++u) b[u] = Bs[kk][tn * 8 + u];
#pragma unroll
            for (int i = 0; i < 8; ++i)
#pragma unroll
                for (int j = 0; j < 8; ++j) acc[i][j] += a[i] * b[j];
        }
        __syncthreads();
    }

    float bias[8];
#pragma unroll
    for (int j = 0; j < 8; ++j) bias[j] = b1[bn * GBN + tn * 8 + j];
#pragma unroll
    for (int i = 0; i < 8; ++i) {
        int brow = tm * 8 + i;
        float* cp = ffx + ((size_t)dt * BATCH + brow) * NR + bn * GBN + tn * 8;
#pragma unroll
        for (int j = 0; j < 8; ++j) cp[j] = acc[i][j] + bias[j];
    }
}

// ---------------- persistent time-loop kernel: 2 independent groups of 128 ----------------
// 256 blocks x 512 threads (8 waves); ~158 KB LDS -> 1 block/CU, all co-resident.
// Group G = blk>>7 owns batches G*64..+64; block gb = blk&127 owns r [gb*32, gb*32+32)
// = neurons [gb*8, gb*8+8). Groups NEVER interact (separate spike slots, separate
// barrier regions, separate output rows) -> straggler tail is max-of-128, and the two
// groups drift independently.
// MFMA: wave (mt=wv>>1, nt2=wv&1): D[16b x 16r] over full K=1024 (32 ksteps x {hi,lo},
// two independent accumulator chains, summed at the end).
// Spike exchange (R9-proven pattern: plain stores + bulk staged loads):
//   raw[slot][G][gb][d]: d = b_local>>2; byte (b_local&3) = 8 spike bits of neurons
//   gb*8..+8. The ballot word IS this layout (tid = b*8+nrn) -> zero packing math.
// Consumer: stage 8 KB coalesced (XOR-swizzled), transpose to lds_mask[64][33]
// (bit p of word w = neuron 32w+p).
// Barrier per group: 8 subgroup counters (16 arrivals each) -> root (+8/epoch);
// leader blocks gb=120..127 poll root, release per-subgroup go words; members poll
// their go line (15 pollers/line).

__global__ __launch_bounds__(512) void persist9(
    const float* __restrict__ alpha1, const float* __restrict__ beta,
    const float* __restrict__ alpha2, float* __restrict__ mem1,
    float* __restrict__ mem2, float* __restrict__ spk2,
    float* __restrict__ d_inp, const uint16_t* __restrict__ fragH_g,
    const uint16_t* __restrict__ fragL_g, const float* __restrict__ W2T,
    const float* __restrict__ ffx, const float* __restrict__ b2v,
    float* __restrict__ out, uint32_t* __restrict__ spkg,
    uint32_t* __restrict__ bar, int t0, int tc, int last, int epoch0) {
    __shared__ __align__(16) uint16_t lds_fh[32768];   // 64 KB  W1h slice hi (32 r)
    __shared__ __align__(16) uint16_t lds_fl[32768];   // 64 KB  W1h slice lo
    __shared__ uint32_t lds_raw[2048];                 // 8 KB   raw spike words (swizzled)
    __shared__ uint32_t lds_mask[64 * 33];             // 8.4 KB per-batch masks (padded)
    __shared__ float lds_part[2560];                   // 10 KB  [4mt][32 r][20 b-pad]

    const int blk = blockIdx.x;
    const int tid = threadIdx.x;
    const int G   = blk >> 7;
    const int gb  = blk & 127;
    const int l   = tid & 63;
    const int wv  = tid >> 6;          // wave 0..7

    // ---- stage weight slice ONCE per chunk (128 KB)
    {
        const float4* sH = (const float4*)(fragH_g + (size_t)gb * 32768);
        const float4* sL = (const float4*)(fragL_g + (size_t)gb * 32768);
        for (int i4 = tid; i4 < 4096; i4 += 512) {
            ((float4*)lds_fh)[i4] = sH[i4];
            ((float4*)lds_fl)[i4] = sL[i4];
        }
    }

    // ---- mfma role: wave (mt, nt2)
    const int mt  = wv >> 1;
    const int nt2 = wv & 1;
    const int arow = mt * 16 + (l & 15);       // local batch row
    const int ksl  = ((l >> 4) & 3) * 8;

    // ---- update role: tid = b_local*8 + nrn
    const int ub = tid >> 3;                   // local batch 0..63
    const int un = tid & 7;                    // neuron-in-block 0..7
    const int bg_ = G * 64 + ub;               // global batch
    const int n_g = gb * 8 + un;               // global neuron
    const int r0  = gb * 32 + un * 4;          // global r base (4 branches)
    const f32x4 bet = *(const f32x4*)&beta[r0];
    const float al  = alpha1[n_g];
    f32x4 di = *(const f32x4*)&d_inp[(size_t)bg_ * NR + r0];
    float mm = mem1[bg_ * NHID + n_g];

    // ---- layer-2 role: blocks gb<16 of each group, 4 batches each
    const int o2 = tid & 31;
    const int sub = tid >> 5;                  // 0..15
    const bool l2blk = (gb < 16) && ((sub & 3) == 0);
    const int b2l = gb * 4 + (sub >> 2);
    const int b2g = G * 64 + b2l;
    float m2 = 0.f, s2v = 0.f, a2 = 0.f, bo = 0.f;
    if (l2blk && o2 < NOUT) {
        a2 = alpha2[o2];
        bo = b2v[o2];
        m2 = mem2[b2g * NOUT + o2];
        s2v = spk2[b2g * NOUT + o2];
    }

    // ---- barrier pointers (group-local region of 1024 dwords)
    uint32_t* breg = bar + (size_t)G * 1024;
    const int sg = gb & 7;
    uint32_t* grpcnt = &breg[32 * (1 + sg)];
    uint32_t* goline = &breg[32 * (9 + sg)];
    const bool leader = (gb >= 120);

    const int iters = tc + (last ? 1 : 0);
    for (int it = 0; it < iters; ++it) {
        const int tt = t0 + it;

        // ---- prefetch ffx (independent of spikes; overlaps spin)
        f32x4 ff = {0.f, 0.f, 0.f, 0.f};
        if (tt < TSTEPS)
            ff = *(const f32x4*)(ffx + (size_t)it * (BATCH * NR) + (size_t)bg_ * NR + r0);

        // ---- wait barrier epoch (group-local; it==0 synced by kernel boundary)
        if (it > 0) {
            if (tid == 0) {
                uint32_t tgt = (uint32_t)(epoch0 + it);
                if (leader) {
                    while (__hip_atomic_load(&breg[0], __ATOMIC_ACQUIRE,
                                             __HIP_MEMORY_SCOPE_AGENT) < 8u * tgt)
                        __builtin_amdgcn_s_sleep(2);
                    __hip_atomic_store(goline, tgt, __ATOMIC_RELEASE,
                                       __HIP_MEMORY_SCOPE_AGENT);
                } else {
                    while (__hip_atomic_load(goline, __ATOMIC_RELAXED,
                                             __HIP_MEMORY_SCOPE_AGENT) < tgt)
                        __builtin_amdgcn_s_sleep(2);
                }
            }
            __syncthreads();
        }

        // ---- stage raw spike words of this group (coalesced, XOR bank-swizzled)
        {
            const uint32_t* spg = spkg + (size_t)((tt + 1) & 1) * 4096 + G * 2048;
#pragma unroll
            for (int k2 = 0; k2 < 4; ++k2) {
                int idx = tid + (k2 << 9);
                lds_raw[idx ^ ((idx >> 6) & 31)] =
                    __hip_atomic_load(&spg[idx], __ATOMIC_RELAXED, __HIP_MEMORY_SCOPE_AGENT);
            }
        }
        __syncthreads();

        // ---- transpose to per-batch 32-word masks: bit p of word w = neuron 32w+p
        {
#pragma unroll
            for (int k2 = 0; k2 < 4; ++k2) {
                int e = tid + (k2 << 9);
                int b = e >> 5, w = e & 31;
                uint32_t word = 0;
#pragma unroll
                for (int m = 0; m < 4; ++m) {
                    int raw = ((w << 2) + m) * 16 + (b >> 2);
                    uint32_t v = lds_raw[raw ^ ((raw >> 6) & 31)];
                    word |= ((v >> ((b & 3) * 8)) & 0xFFu) << (m * 8);
                }
                lds_mask[b * 33 + w] = word;
            }
        }
        __syncthreads();

        // ---------- phase 1a: MFMA recurrent matmul (full K per wave, 2 acc chains) ----------
        if (tt < TSTEPS) {
            f32x4 accH = {0.f, 0.f, 0.f, 0.f};
            f32x4 accL = {0.f, 0.f, 0.f, 0.f};
            const int maskbase = arow * 33;
            const int fbase = nt2 * 32;
#pragma unroll 4
            for (int ks = 0; ks < 32; ++ks) {
                uint32_t bits = (lds_mask[maskbase + ks] >> ksl) & 0xFFu;
                union { uint32_t u[4]; s16x8 v; } a;
                a.u[0] = ((bits & 1u)  ? 0x3F80u : 0u) | ((bits & 2u)   ? 0x3F800000u : 0u);
                a.u[1] = ((bits & 4u)  ? 0x3F80u : 0u) | ((bits & 8u)   ? 0x3F800000u : 0u);
                a.u[2] = ((bits & 16u) ? 0x3F80u : 0u) | ((bits & 32u)  ? 0x3F800000u : 0u);
                a.u[3] = ((bits & 64u) ? 0x3F80u : 0u) | ((bits & 128u) ? 0x3F800000u : 0u);
                const s16x8 bh = *(const s16x8*)&lds_fh[((fbase + ks) * 64 + l) * 8];
                const s16x8 bl = *(const s16x8*)&lds_fl[((fbase + ks) * 64 + l) * 8];
                accH = __builtin_amdgcn_mfma_f32_16x16x32_bf16(a.v, bh, accH, 0, 0, 0);
                accL = __builtin_amdgcn_mfma_f32_16x16x32_bf16(a.v, bl, accL, 0, 0, 0);
            }
            f32x4 d;
#pragma unroll
            for (int q = 0; q < 4; ++q) d[q] = accH[q] + accL[q];
            // parts [mt][32 r_local][20 b-pad]; C/D col=l&15 (r), row=(l>>4)*4+q (b) [m89]
            float* pp = lds_part + ((mt * 32 + nt2 * 16 + (l & 15)) * 20 + ((l >> 4) & 3) * 4);
            *(float4*)pp = *(float4*)&d;
        }
        __syncthreads();

        // ---------- phase 1b: dendrite + mem1 + spike (plain raw stores) ----------
        if (tt < TSTEPS) {
            const int rl0 = un * 4;
            float s[4];
#pragma unroll
            for (int q = 0; q < 4; ++q)
                s[q] = lds_part[((ub >> 4) * 32 + rl0 + q) * 20 + (ub & 15)];
#pragma unroll
            for (int q = 0; q < 4; ++q)
                di[q] = bet[q] * di[q] + (1.f - bet[q]) * (s[q] + ff[q]);
            float lsum = (di[0] + di[1]) + (di[2] + di[3]);
            float sp_prev = (float)((lds_mask[ub * 33 + (n_g >> 5)] >> (n_g & 31)) & 1u);
            float mn = mm * al + (1.f - al) * lsum - VTH * sp_prev;
            mm = mn;
            bool spk = (mn - VTH) > 0.f;
            unsigned long long bal = __ballot(spk);   // bit l = (batch wv*8 + l>>3, nrn l&7)
            uint32_t* spn = spkg + (size_t)(tt & 1) * 4096 + G * 2048;
            if (l == 0)
                __hip_atomic_store(&spn[gb * 16 + wv * 2], (uint32_t)bal,
                                   __ATOMIC_RELAXED, __HIP_MEMORY_SCOPE_AGENT);
            if (l == 32)
                __hip_atomic_store(&spn[gb * 16 + wv * 2 + 1], (uint32_t)(bal >> 32),
                                   __ATOMIC_RELAXED, __HIP_MEMORY_SCOPE_AGENT);
        }

        // ---- arrive (stores drained by the barrier's vmcnt(0))
        __syncthreads();
        if (it + 1 < iters && tid == 0) {
            uint32_t e16 = 16u * (uint32_t)(epoch0 + it + 1);
            uint32_t old = __hip_atomic_fetch_add(grpcnt, 1u, __ATOMIC_RELEASE,
                                                  __HIP_MEMORY_SCOPE_AGENT);
            if (old == e16 - 1u)    // 16th arrival of this subgroup this epoch
                __hip_atomic_fetch_add(&breg[0], 1u, __ATOMIC_RELEASE,
                                       __HIP_MEMORY_SCOPE_AGENT);
        }

        // ---------- phase 2 (step tt-1): layer 2 + log_softmax (hides in spin window) ----------
        if (tt > 0 && l2blk) {
            const uint32_t* mw = &lds_mask[b2l * 33];
            float d2 = bo;
            for (int w = 0; w < 32; ++w) {
                uint32_t bits = mw[w];
                while (bits) {
                    int p = __builtin_ctz(bits);
                    bits &= bits - 1;
                    d2 += W2T[(((w << 5) + p) << 5) + o2];
                }
            }
            float m2n = m2 * a2 + (1.f - a2) * d2 - VTH * s2v;
            m2 = m2n;
            s2v = ((m2n - VTH) > 0.f) ? 1.f : 0.f;
            float v = (o2 < NOUT) ? m2n : -3.4e38f;
#pragma unroll
            for (int off = 16; off >= 1; off >>= 1) v = fmaxf(v, __shfl_xor(v, off, 32));
            float e = (o2 < NOUT) ? expf(m2n - v) : 0.f;
            float ssum = e;
#pragma unroll
            for (int off = 16; off >= 1; off >>= 1) ssum += __shfl_xor(ssum, off, 32);
            if (o2 < NOUT) out[((size_t)b2g * NOUT + o2) * TSTEPS + (tt - 1)] = (m2n - v) - logf(ssum);
        }
    }

    // ---- save state for next chunk
    *(f32x4*)&d_inp[(size_t)bg_ * NR + r0] = di;
    mem1[bg_ * NHID + n_g] = mm;
    if (l2blk && o2 < NOUT) {
        mem2[b2g * NOUT + o2] = m2;
        spk2[b2g * NOUT + o2] = s2v;
    }
}

// ---------------- host ----------------

extern "C" void kernel_launch(void* const* d_in, const int* in_sizes, int n_in,
                              void* d_out, int out_size, void* d_ws, size_t ws_size,
                              hipStream_t stream) {
    const float* x      = (const float*)d_in[0];
    const float* W1     = (const float*)d_in[1];
    const float* b1     = (const float*)d_in[2];
    const float* tau_m1 = (const float*)d_in[3];
    const float* tau_n  = (const float*)d_in[4];
    const float* W2     = (const float*)d_in[5];
    const float* b2     = (const float*)d_in[6];
    const float* tau_m2 = (const float*)d_in[7];
    const float* mem1_0 = (const float*)d_in[8];
    const float* mem2_0 = (const float*)d_in[9];
    const int*   mask   = (const int*)d_in[10];
    float* out = (float*)d_out;

    float* ws = (float*)d_ws;
    size_t F = 0;
    float* alpha1 = ws + F; F += 1024;
    float* beta   = ws + F; F += 4096;
    float* alpha2 = ws + F; F += 32;
    float* mem1   = ws + F; F += BATCH * NHID;
    float* mem2   = ws + F; F += BATCH * NOUT;
    float* spk2   = ws + F; F += BATCH * NOUT;
    float* d_inp  = ws + F; F += BATCH * NR;
    float* W1xT   = ws + F; F += (size_t)NIN * NR;
    uint16_t* fragH = (uint16_t*)(ws + F); F += (size_t)(128 << 15) / 2;   // W1h frags hi
    uint16_t* fragL = (uint16_t*)(ws + F); F += (size_t)(128 << 15) / 2;   // W1h frags lo
    float* W2T    = ws + F; F += NHID * 32;
    uint32_t* spkg = (uint32_t*)(ws + F); F += 8192;   // 2 slots x 2 groups x 2048
    uint32_t* bar  = (uint32_t*)(ws + F); F += 2048;   // 2 x 1024 group barrier regions
    float* ffx = ws + F;

    size_t ws_f = ws_size / 4;
    size_t avail = (ws_f > F) ? (ws_f - F) : 0;
    size_t per_t = (size_t)BATCH * NR;          // 524288 floats per timestep
    int Tc = (int)(avail / per_t);
    if (Tc < 1) Tc = 1;
    if (Tc > TSTEPS) Tc = TSTEPS;

    hipLaunchKernelGGL(setup_small, dim3(128), dim3(256), 0, stream,
                       tau_m1, tau_n, tau_m2, W2, alpha1, beta, alpha2, W2T);
    hipLaunchKernelGGL(setup_weights, dim3(2048), dim3(256), 0, stream,
                       W1, mask, W1xT, fragH, fragL);
    hipLaunchKernelGGL(init_state, dim3(2048), dim3(256), 0, stream,
                       mem1_0, mem2_0, mem1, mem2, spk2, d_inp, spkg, bar);

    int chunk_start = 0;
    int barriers_done = 0;
    while (chunk_start < TSTEPS) {
        int tc = TSTEPS - chunk_start;
        if (tc > Tc) tc = Tc;
        int last = (chunk_start + tc >= TSTEPS) ? 1 : 0;

        hipLaunchKernelGGL(ffx_gemm, dim3(tc, 32), dim3(256), 0, stream,
                           x, W1xT, b1, ffx, chunk_start);
        hipLaunchKernelGGL(persist9, dim3(256), dim3(512), 0, stream,
                           alpha1, beta, alpha2, mem1, mem2, spk2, d_inp, fragH, fragL,
                           W2T, ffx, b2, out, spkg, bar, chunk_start, tc, last, barriers_done);

        int iters = tc + (last ? 1 : 0);
        barriers_done += iters - 1;
        chunk_start += tc;
    }
}